// Round 17
// baseline (2436.848 us; speedup 1.0000x reference)
//
#include <hip/hip_runtime.h>
#include <hip/hip_bf16.h>
#include <math.h>

#define BB 1024
#define TT 64
#define OBSN 64
#define ACTN 8
#define STOCHN 32
#define DETERN 512
#define HIDN 512
#define G3N 1536
#define CATPI 40
#define OUTC 672
#define LNEPS 1e-3f
#define MINSTD 0.1f
#define UPDBIAS -1.0f

typedef __attribute__((ext_vector_type(8))) short short8;
typedef __attribute__((ext_vector_type(4))) float f32x4;

__device__ __forceinline__ float sigmoidf_(float x) { return 1.f / (1.f + expf(-x)); }
__device__ __forceinline__ float siluf_(float x) { return x / (1.f + expf(-x)); }
__device__ __forceinline__ float softplusf_(float x) { return (x > 20.f) ? x : log1pf(expf(x)); }

__device__ __forceinline__ float b2f(short u) {
    unsigned x = ((unsigned)(unsigned short)u) << 16;
    return __builtin_bit_cast(float, x);
}
__device__ __forceinline__ short f2b(float f) {
    __hip_bfloat16 h = __float2bfloat16(f);
    return __builtin_bit_cast(short, h);
}

__device__ __forceinline__ f32x4 mfma16(short8 a, short8 b, f32x4 c) {
    return __builtin_amdgcn_mfma_f32_16x16x32_bf16(a, b, c, 0, 0, 0);
}

__device__ __forceinline__ void gload_lds16(const void* g, void* l) {
    __builtin_amdgcn_global_load_lds((const __attribute__((address_space(1))) void*)g,
                                     (__attribute__((address_space(3))) void*)l, 16, 0, 0);
}

__device__ __forceinline__ void wred2(float& a, float& b) {
#pragma unroll
    for (int off = 32; off; off >>= 1) {
        a += __shfl_xor(a, off);
        b += __shfl_xor(b, off);
    }
}

// ---- swizzled bf16 [R][512] LDS tile: row stride 1024 B, 16B slots XOR'd by row&7 ----
__device__ __forceinline__ short8 frag_ld(const short* base, int row, int ks, int lk) {
    int slot = (ks * 4 + lk) ^ (row & 7);
    return *(const short8*)((const char*)base + row * 1024 + (slot << 4));
}
// ---- swizzled bf16 rows of 64 K (128 B stride) ----
__device__ __forceinline__ short8 frag_ld64(const short* base, int row, int ks, int lk) {
    int slot = ((ks * 4 + lk) ^ (row & 7)) & 7;
    return *(const short8*)((const char*)base + row * 128 + (slot << 4));
}

// ==== GEMM tile machinery, parameterized: BM = AMT*32, BN = NFC*32 ====
template <int NFC, int AMT>
__device__ __forceinline__ void stage_tile(const __hip_bfloat16* A0, int ld0, int K0, const __hip_bfloat16* A1,
                                           int ld1, const __hip_bfloat16* Wt, int ldW, int wn0, int cm0, int k0,
                                           char* smA, char* smB) {
    int tid = threadIdx.x, wid = tid >> 6, lane = tid & 63;
    int rseg = lane >> 3, slot = lane & 7;
    const __hip_bfloat16* Ab;
    int ldA, kloc;
    if (k0 < K0) {
        Ab = A0; ldA = ld0; kloc = k0;
    } else {
        Ab = A1; ldA = ld1; kloc = k0 - K0;
    }
#pragma unroll
    for (int i = 0; i < AMT; ++i) {
        int seg = wid * AMT + i;
        int row = seg * 8 + rseg;
        int kk = kloc + ((slot ^ (row & 7)) << 3);
        gload_lds16(Ab + (size_t)(cm0 + row) * ldA + kk, smA + seg * 1024);
    }
#pragma unroll
    for (int i = 0; i < NFC; ++i) {
        int seg = wid * NFC + i;
        int row = seg * 8 + rseg;
        int kk = k0 + ((slot ^ (row & 7)) << 3);
        gload_lds16(Wt + (size_t)(wn0 + row) * ldW + kk, smB + seg * 1024);
    }
}

template <int NFC, int AMT>
__device__ __forceinline__ void compute_tile(const char* smA, const char* smB, f32x4 (&acc)[AMT][NFC]) {
    int lane = threadIdx.x & 63, wid = threadIdx.x >> 6;
    int wr = wid >> 1, wc = wid & 1;
#pragma unroll
    for (int ks = 0; ks < 2; ++ks) {
        short8 af[AMT], bfr[NFC];
        int kslot = ks * 4 + (lane >> 4);
#pragma unroll
        for (int m = 0; m < AMT; ++m) {
            int row = wr * (16 * AMT) + m * 16 + (lane & 15);
            af[m] = *(const short8*)(smA + row * 128 + ((kslot ^ (row & 7)) << 4));
        }
#pragma unroll
        for (int n = 0; n < NFC; ++n) {
            int row = wc * (16 * NFC) + n * 16 + (lane & 15);
            bfr[n] = *(const short8*)(smB + row * 128 + ((kslot ^ (row & 7)) << 4));
        }
#pragma unroll
        for (int m = 0; m < AMT; ++m)
#pragma unroll
            for (int n = 0; n < NFC; ++n) acc[m][n] = mfma16(af[m], bfr[n], acc[m][n]);
    }
}

template <int NFC, int AMT>
__device__ __forceinline__ void gemm_tile_db(const __hip_bfloat16* A0, int ld0, int K0, const __hip_bfloat16* A1,
                                             int ld1, const __hip_bfloat16* Wt, int ldW, int wn0, float* C, int ldc,
                                             int cm0, int cn0, int nK, char* smem) {
    char* smA[2] = {smem, smem + AMT * 4096};
    char* smB[2] = {smem + 2 * AMT * 4096, smem + 2 * AMT * 4096 + NFC * 4096};
    f32x4 acc[AMT][NFC] = {};
    stage_tile<NFC, AMT>(A0, ld0, K0, A1, ld1, Wt, ldW, wn0, cm0, 0, smA[0], smB[0]);
    for (int kt = 0; kt < nK; ++kt) {
        if (kt + 1 < nK) {
            stage_tile<NFC, AMT>(A0, ld0, K0, A1, ld1, Wt, ldW, wn0, cm0, (kt + 1) * 64, smA[(kt + 1) & 1],
                                 smB[(kt + 1) & 1]);
            constexpr int NL = NFC + AMT;
            if constexpr (NL == 5) asm volatile("s_waitcnt vmcnt(5)" ::: "memory");
            else if constexpr (NL == 4) asm volatile("s_waitcnt vmcnt(4)" ::: "memory");
            else asm volatile("s_waitcnt vmcnt(3)" ::: "memory");
        } else {
            asm volatile("s_waitcnt vmcnt(0)" ::: "memory");
        }
        __builtin_amdgcn_s_barrier();
        compute_tile<NFC, AMT>(smA[kt & 1], smB[kt & 1], acc);
        __builtin_amdgcn_s_barrier();
    }
    int lane = threadIdx.x & 63, wid = threadIdx.x >> 6;
    int wr = wid >> 1, wc = wid & 1;
    int r0 = cm0 + wr * (16 * AMT) + ((lane >> 4) << 2);
    int c0 = cn0 + wc * 16 * NFC + (lane & 15);
#pragma unroll
    for (int m = 0; m < AMT; ++m)
#pragma unroll
        for (int n = 0; n < NFC; ++n)
#pragma unroll
            for (int i = 0; i < 4; ++i)
                C[(size_t)(r0 + m * 16 + i) * ldc + c0 + n * 16] = acc[m][n][i];
}

// ==== K1: GRU GEMM, K-split 2-way: 1024 blocks of 32x96xK512 (4 blocks/CU) ====
__global__ __launch_bounds__(256) void k_gemm_gru(const __hip_bfloat16* __restrict__ xbf,
                                                  const __hip_bfloat16* __restrict__ dbf,
                                                  const __hip_bfloat16* __restrict__ WgT,
                                                  float* __restrict__ gates) {
    __shared__ __align__(16) char smem[32768];
    int bm = blockIdx.x & 31, bn = (blockIdx.x >> 5) & 15, kh = blockIdx.x >> 9;
    const __hip_bfloat16* A = kh ? dbf : xbf;
    gemm_tile_db<3, 1>(A, 512, 512, A, 512, WgT + kh * 512, 1024, bn * 96,
                       gates + (size_t)kh * BB * G3N, G3N, bm * 32, bn * 96, 8, smem);
}

// ==== K2: LN(gates0+gates1) + GRU update. 256 blocks x 256 thr (4 rows/block) ====
__global__ __launch_bounds__(256) void k_update(int t, const float* __restrict__ gates,
                                                const float* __restrict__ g_gru, const float* __restrict__ b_gru,
                                                float* __restrict__ deter, __hip_bfloat16* __restrict__ dbf,
                                                float* __restrict__ out) {
    const int tid = threadIdx.x;
    const int prow = tid >> 6, l = tid & 63;
    const int gr = blockIdx.x * 4 + prow;
    const int j0 = l * 8;
    const float* gp0 = gates + (size_t)gr * G3N;
    const float* gp1 = gates + (size_t)BB * G3N + (size_t)gr * G3N;
    float g0[8], g1[8], g2[8];
    float s = 0.f, q = 0.f;
#pragma unroll
    for (int e = 0; e < 8; e += 4) {
        f32x4 a0 = *(const f32x4*)(gp0 + j0 + e);
        f32x4 b0 = *(const f32x4*)(gp0 + 512 + j0 + e);
        f32x4 c0 = *(const f32x4*)(gp0 + 1024 + j0 + e);
        f32x4 a1 = *(const f32x4*)(gp1 + j0 + e);
        f32x4 b1 = *(const f32x4*)(gp1 + 512 + j0 + e);
        f32x4 c1 = *(const f32x4*)(gp1 + 1024 + j0 + e);
#pragma unroll
        for (int u = 0; u < 4; ++u) {
            float a = a0[u] + a1[u], b = b0[u] + b1[u], c = c0[u] + c1[u];
            g0[e + u] = a;
            g1[e + u] = b;
            g2[e + u] = c;
            s += a + b + c;
            q += a * a + b * b + c * c;
        }
    }
    wred2(s, q);
    float m = s * (1.f / 1536.f), iv = rsqrtf(q * (1.f / 1536.f) - m * m + LNEPS);
    float dn[8];
    float* dp = deter + (size_t)gr * 512 + j0;
#pragma unroll
    for (int e = 0; e < 8; e += 4) {
        f32x4 dv = *(const f32x4*)(dp + e);
#pragma unroll
        for (int u = 0; u < 4; ++u) {
            int col = j0 + e + u;
            float rv = sigmoidf_((g0[e + u] - m) * iv * g_gru[col] + b_gru[col]);
            float cv = (g1[e + u] - m) * iv * g_gru[512 + col] + b_gru[512 + col];
            float uv = sigmoidf_((g2[e + u] - m) * iv * g_gru[1024 + col] + b_gru[1024 + col] + UPDBIAS);
            dn[e + u] = uv * siluf_(rv * cv) + (1.f - uv) * dv[u];
        }
    }
    size_t ob = ((size_t)gr * TT + t) * OUTC + 160 + j0;
    short8 h;
#pragma unroll
    for (int e = 0; e < 8; e += 4) {
        *(f32x4*)(dp + e) = *(const f32x4*)&dn[e];
        *(f32x4*)(out + ob + e) = *(const f32x4*)&dn[e];
    }
#pragma unroll
    for (int u = 0; u < 8; ++u) h[u] = f2b(dn[u]);
    *(short8*)(dbf + (size_t)gr * 512 + j0) = h;
}

// ==== K3: hq partial GEMMs, K-split at 320: 512 blocks of 32x64 (2 blocks/CU) ====
__global__ __launch_bounds__(256) void k_gemm_hq(int t, const __hip_bfloat16* __restrict__ dbf,
                                                 const __hip_bfloat16* __restrict__ obsbf,
                                                 const __hip_bfloat16* __restrict__ WpnT,
                                                 float* __restrict__ hq_raw) {
    __shared__ __align__(16) char smem[24576];
    int bm = blockIdx.x & 31, bn = (blockIdx.x >> 5) & 7, kh = blockIdx.x >> 8;
    if (kh == 0) {
        // K 0..319 of deter (5 tiles)
        gemm_tile_db<2, 1>(dbf, 512, 512, dbf, 512, WpnT, 576, bn * 64, hq_raw, 512, bm * 32, bn * 64, 5, smem);
    } else {
        // K 320..511 of deter (3 tiles) + obs (1 tile)
        gemm_tile_db<2, 1>(dbf + 320, 512, 192, obsbf + (size_t)t * OBSN, TT * OBSN, WpnT + 320, 576, bn * 64,
                           hq_raw + (size_t)BB * 512, 512, bm * 32, bn * 64, 4, smem);
    }
}

// ==== K4: LN(hq0+hq1)+silu, qs stats, outputs, reset, next prior_in. 256 blocks x 256 thr ====
__global__ __launch_bounds__(256) void k_finish(int t, const float* __restrict__ hq_raw,
                                                const float* __restrict__ g_pn, const float* __restrict__ b_pn,
                                                const __hip_bfloat16* __restrict__ WptT,
                                                const float* __restrict__ b_pt, const int* __restrict__ isf,
                                                const float* __restrict__ action, const float* __restrict__ dinit,
                                                const float* __restrict__ sinit, float* __restrict__ deter,
                                                __hip_bfloat16* __restrict__ dbf,
                                                const __hip_bfloat16* __restrict__ Wpibf,
                                                const float* __restrict__ g_pi, const float* __restrict__ b_pi,
                                                __hip_bfloat16* __restrict__ xbf, float* __restrict__ out) {
    __shared__ float hql[4][512];
    __shared__ float a_ls[4][40];
    const int wid = threadIdx.x >> 6, l = threadIdx.x & 63;
    const int gr = blockIdx.x * 4 + wid;
    const int j0 = l * 8;
    const float* hr0 = hq_raw + (size_t)gr * 512;
    const float* hr1 = hq_raw + (size_t)BB * 512 + (size_t)gr * 512;
    float h[8];
    {
        f32x4 a0 = *(const f32x4*)(hr0 + j0);
        f32x4 a1 = *(const f32x4*)(hr0 + j0 + 4);
        f32x4 b0 = *(const f32x4*)(hr1 + j0);
        f32x4 b1 = *(const f32x4*)(hr1 + j0 + 4);
#pragma unroll
        for (int e = 0; e < 4; ++e) {
            h[e] = a0[e] + b0[e];
            h[4 + e] = a1[e] + b1[e];
        }
    }
    float s = 0.f, q = 0.f;
#pragma unroll
    for (int e = 0; e < 8; ++e) {
        s += h[e];
        q += h[e] * h[e];
    }
    wred2(s, q);
    float m = s * (1.f / 512.f), iv = rsqrtf(q * (1.f / 512.f) - m * m + LNEPS);
#pragma unroll
    for (int e = 0; e < 8; ++e) h[e] = siluf_((h[e] - m) * iv * g_pn[j0 + e] + b_pn[j0 + e]);
    *(f32x4*)&hql[wid][j0] = *(const f32x4*)&h[0];
    *(f32x4*)&hql[wid][j0 + 4] = *(const f32x4*)&h[4];
    __syncthreads();
    float acc = b_pt[l];
    const __hip_bfloat16* wr = WptT + (size_t)l * 512;
    const float* hq = hql[wid];
#pragma unroll 4
    for (int k0 = 0; k0 < 512; k0 += 8) {
        short8 w = *(const short8*)(wr + k0);
        f32x4 a0 = *(const f32x4*)(hq + k0);
        f32x4 a1 = *(const f32x4*)(hq + k0 + 4);
#pragma unroll
        for (int e = 0; e < 4; ++e) {
            acc += b2f(w[e]) * a0[e];
            acc += b2f(w[4 + e]) * a1[e];
        }
    }
    size_t ob = ((size_t)gr * TT + t) * OUTC;
    if (l < 32) {
        out[ob + l] = acc;
        out[ob + 64 + l] = acc;
    } else {
        out[ob + 32 + (l - 32)] = softplusf_(acc) + MINSTD;
    }
    if (t + 1 >= TT) return;
    int f1 = isf[(size_t)gr * TT + t + 1] > 0;
    if (l < 32)
        a_ls[wid][l] = f1 ? sinit[l] : acc;
    else if (l < 40)
        a_ls[wid][l] = f1 ? 0.f : action[((size_t)gr * TT + t + 1) * ACTN + (l - 32)];
    if (f1) {
        f32x4 d0 = *(const f32x4*)(dinit + j0);
        f32x4 d1 = *(const f32x4*)(dinit + j0 + 4);
        *(f32x4*)(deter + (size_t)gr * 512 + j0) = d0;
        *(f32x4*)(deter + (size_t)gr * 512 + j0 + 4) = d1;
        short8 db;
#pragma unroll
        for (int e = 0; e < 4; ++e) {
            db[e] = f2b(d0[e]);
            db[4 + e] = f2b(d1[e]);
        }
        *(short8*)(dbf + (size_t)gr * 512 + j0) = db;
    }
    __syncthreads();
    float o[8] = {};
    const float* a_s = a_ls[wid];
    for (int k = 0; k < CATPI; ++k) {
        float a = a_s[k];
        short8 w = *(const short8*)(Wpibf + k * 512 + j0);
#pragma unroll
        for (int e = 0; e < 8; ++e) o[e] += a * b2f(w[e]);
    }
    float s2 = 0.f, q2 = 0.f;
#pragma unroll
    for (int e = 0; e < 8; ++e) {
        s2 += o[e];
        q2 += o[e] * o[e];
    }
    wred2(s2, q2);
    float m2 = s2 * (1.f / 512.f), iv2 = rsqrtf(q2 * (1.f / 512.f) - m2 * m2 + LNEPS);
    short8 xo;
#pragma unroll
    for (int e = 0; e < 8; ++e) xo[e] = f2b(siluf_((o[e] - m2) * iv2 * g_pi[j0 + e] + b_pi[j0 + e]));
    *(short8*)(xbf + (size_t)gr * 512 + j0) = xo;
}

// ==== deferred p_mean/p_std: 1024 blocks x 512 thr, M=64/block (round-14 validated: 148 us) ====
__global__ __launch_bounds__(512) void k_post_p(const float* __restrict__ outr,
                                                const __hip_bfloat16* __restrict__ WpoT,
                                                const float* __restrict__ g_po, const float* __restrict__ b_po,
                                                const __hip_bfloat16* __restrict__ WpsT,
                                                const float* __restrict__ b_ps, float* __restrict__ out) {
    __shared__ short Abuf[64 * 512];
    __shared__ __align__(16) short Wbuf[512 * 64];
    __shared__ float red[8 * 64 * 2];
    __shared__ float redc[64 * 2];
    const int tid = threadIdx.x, wid = tid >> 6, lane = tid & 63, lr = lane & 15, lk = lane >> 4;
    const int base = blockIdx.x * 64;
    const int c0 = wid * 64 + lr;

#pragma unroll
    for (int it = 0; it < 8; ++it) {
        int idx = it * 512 + tid;
        int row = idx >> 6, slot = idx & 63;
        int k = (slot ^ (row & 7)) << 3;
        const float* src = outr + ((size_t)(base + row) * OUTC + 160 + k);
        f32x4 a = *(const f32x4*)src;
        f32x4 bb = *(const f32x4*)(src + 4);
        short8 v;
#pragma unroll
        for (int e = 0; e < 4; ++e) {
            v[e] = f2b(a[e]);
            v[4 + e] = f2b(bb[e]);
        }
        *(short8*)((char*)Abuf + idx * 16) = v;
    }
    auto stageW = [&](int ck) {
#pragma unroll
        for (int i = 0; i < 8; ++i) {
            int seg = wid * 8 + i;
            int row = seg * 8 + (lane >> 3);
            int kk = ck * 64 + (((lane & 7) ^ (row & 7)) << 3);
            gload_lds16(WpoT + (size_t)row * 512 + kk, (char*)Wbuf + seg * 1024);
        }
    };
    __syncthreads();
    f32x4 acc[4][4] = {};
    for (int ck = 0; ck < 8; ++ck) {
        stageW(ck);
        asm volatile("s_waitcnt vmcnt(0)" ::: "memory");
        __builtin_amdgcn_s_barrier();
#pragma unroll
        for (int ks = 0; ks < 2; ++ks) {
            short8 af[4];
#pragma unroll
            for (int rt = 0; rt < 4; ++rt) af[rt] = frag_ld(Abuf, rt * 16 + lr, ck * 2 + ks, lk);
#pragma unroll
            for (int f = 0; f < 4; ++f) {
                short8 bf = frag_ld64(Wbuf, c0 + f * 16, ks, lk);
#pragma unroll
                for (int rt = 0; rt < 4; ++rt) acc[rt][f] = mfma16(af[rt], bf, acc[rt][f]);
            }
        }
        __builtin_amdgcn_s_barrier();
    }
#pragma unroll
    for (int qq = 0; qq < 8; ++qq) {
        int sI = qq * 512 + tid;
        int row = sI >> 6, slot = sI & 63;
        int k = (slot ^ (row & 7)) << 3;
        gload_lds16(WpsT + (size_t)row * 512 + k, (char*)Abuf + (qq * 512 + wid * 64) * 16);
    }
    {
        float s[4][4], q[4][4];
#pragma unroll
        for (int rt = 0; rt < 4; ++rt)
#pragma unroll
            for (int i = 0; i < 4; ++i) {
                float ss = 0.f, qq2 = 0.f;
#pragma unroll
                for (int f = 0; f < 4; ++f) {
                    float v = acc[rt][f][i];
                    ss += v;
                    qq2 += v * v;
                }
                s[rt][i] = ss;
                q[rt][i] = qq2;
            }
#pragma unroll
        for (int msk = 1; msk <= 8; msk <<= 1)
#pragma unroll
            for (int rt = 0; rt < 4; ++rt)
#pragma unroll
                for (int i = 0; i < 4; ++i) {
                    s[rt][i] += __shfl_xor(s[rt][i], msk);
                    q[rt][i] += __shfl_xor(q[rt][i], msk);
                }
        if (lr == 0)
#pragma unroll
            for (int rt = 0; rt < 4; ++rt)
#pragma unroll
                for (int i = 0; i < 4; ++i) {
                    int row = rt * 16 + lk * 4 + i;
                    red[(wid * 64 + row) * 2 + 0] = s[rt][i];
                    red[(wid * 64 + row) * 2 + 1] = q[rt][i];
                }
        __syncthreads();
        if (tid < 128) {
            int row = tid >> 1, v = tid & 1;
            float a = 0.f;
#pragma unroll
            for (int w = 0; w < 8; ++w) a += red[(w * 64 + row) * 2 + v];
            redc[row * 2 + v] = a;
        }
        __syncthreads();
#pragma unroll
        for (int rt = 0; rt < 4; ++rt)
#pragma unroll
            for (int i = 0; i < 4; ++i) {
                int row = rt * 16 + lk * 4 + i;
                float mm = redc[row * 2] * (1.f / 512.f);
                float vv = redc[row * 2 + 1] * (1.f / 512.f) - mm * mm;
                float ivv = rsqrtf(vv + LNEPS);
#pragma unroll
                for (int f = 0; f < 4; ++f) {
                    int col = c0 + f * 16;
                    float v = siluf_((acc[rt][f][i] - mm) * ivv * g_po[col] + b_po[col]);
                    *(short*)((char*)Wbuf + row * 1024 +
                              ((((col >> 3) ^ (row & 7)) << 4) | ((col & 7) << 1))) = f2b(v);
                }
            }
    }
    asm volatile("s_waitcnt vmcnt(0)" ::: "memory");
    __syncthreads();
    if (wid < 4) {
        int col = wid * 16 + lr;
        f32x4 ap[4] = {};
#pragma unroll 2
        for (int ks = 0; ks < 16; ++ks) {
            short8 bfr = frag_ld(Abuf, col, ks, lk);
#pragma unroll
            for (int rt = 0; rt < 4; ++rt) {
                short8 a = frag_ld(Wbuf, rt * 16 + lr, ks, lk);
                ap[rt] = mfma16(a, bfr, ap[rt]);
            }
        }
        float bias = b_ps[col];
#pragma unroll
        for (int rt = 0; rt < 4; ++rt)
#pragma unroll
            for (int i = 0; i < 4; ++i) {
                int gidx = base + rt * 16 + lk * 4 + i;
                float v = ap[rt][i] + bias;
                if (col < 32)
                    out[(size_t)gidx * OUTC + 96 + col] = v;
                else
                    out[(size_t)gidx * OUTC + 128 + (col - 32)] = softplusf_(v) + MINSTD;
            }
    }
}

// ==== t=0 state + first prior_in (256 blocks x 256 thr, 4 rows) ====
__global__ __launch_bounds__(256) void k_prior0(const int* __restrict__ isf, const float* __restrict__ action,
                                                const float* __restrict__ dinit, const float* __restrict__ sinit,
                                                const __hip_bfloat16* __restrict__ Wpibf,
                                                const float* __restrict__ g_pi, const float* __restrict__ b_pi,
                                                float* __restrict__ deter0, __hip_bfloat16* __restrict__ dbf,
                                                __hip_bfloat16* __restrict__ xbf) {
    __shared__ float a_ls[4][40];
    const int wid = threadIdx.x >> 6, l = threadIdx.x & 63;
    const int gr = blockIdx.x * 4 + wid;
    const int j0 = l * 8;
    int f0 = isf[(size_t)gr * TT] > 0;
    if (l < 32)
        a_ls[wid][l] = sinit[l];
    else if (l < 40)
        a_ls[wid][l] = f0 ? 0.f : action[(size_t)gr * TT * ACTN + (l - 32)];
    f32x4 d0 = *(const f32x4*)(dinit + j0);
    f32x4 d1 = *(const f32x4*)(dinit + j0 + 4);
    *(f32x4*)(deter0 + (size_t)gr * 512 + j0) = d0;
    *(f32x4*)(deter0 + (size_t)gr * 512 + j0 + 4) = d1;
    short8 db;
#pragma unroll
    for (int e = 0; e < 4; ++e) {
        db[e] = f2b(d0[e]);
        db[4 + e] = f2b(d1[e]);
    }
    *(short8*)(dbf + (size_t)gr * 512 + j0) = db;
    __syncthreads();
    float o[8] = {};
    const float* a_s = a_ls[wid];
    for (int k = 0; k < CATPI; ++k) {
        float a = a_s[k];
        short8 w = *(const short8*)(Wpibf + k * 512 + j0);
#pragma unroll
        for (int e = 0; e < 8; ++e) o[e] += a * b2f(w[e]);
    }
    float s2 = 0.f, q2 = 0.f;
#pragma unroll
    for (int e = 0; e < 8; ++e) {
        s2 += o[e];
        q2 += o[e] * o[e];
    }
    wred2(s2, q2);
    float m2 = s2 * (1.f / 512.f), iv2 = rsqrtf(q2 * (1.f / 512.f) - m2 * m2 + LNEPS);
    short8 xo;
#pragma unroll
    for (int e = 0; e < 8; ++e) xo[e] = f2b(siluf_((o[e] - m2) * iv2 * g_pi[j0 + e] + b_pi[j0 + e]));
    *(short8*)(xbf + (size_t)gr * 512 + j0) = xo;
}

// ---- block-wide reduction (k_init only) ----
template <int NV>
__device__ __forceinline__ void breduce(float* v, float* red, int nwaves) {
    __syncthreads();
#pragma unroll
    for (int off = 32; off > 0; off >>= 1)
#pragma unroll
        for (int q = 0; q < NV; ++q) v[q] += __shfl_down(v[q], off);
    int lane = threadIdx.x & 63, w = threadIdx.x >> 6;
    if (lane == 0)
        for (int q = 0; q < NV; ++q) red[w * NV + q] = v[q];
    __syncthreads();
    if ((int)threadIdx.x < NV) {
        float s = 0.f;
        for (int ww = 0; ww < nwaves; ++ww) s += red[ww * NV + threadIdx.x];
        red[nwaves * NV + threadIdx.x] = s;
    }
    __syncthreads();
#pragma unroll
    for (int q = 0; q < NV; ++q) v[q] = red[nwaves * NV + q];
}

__global__ __launch_bounds__(512) void k_init(const float* __restrict__ init_deter, const float* __restrict__ W_po,
                                              const float* __restrict__ g_po, const float* __restrict__ b_po,
                                              const float* __restrict__ W_ps, const float* __restrict__ b_ps,
                                              float* __restrict__ dinit, float* __restrict__ sinit) {
    __shared__ float d_s[512], h_s[512], red[40];
    int tid = threadIdx.x;
    float dv = tanhf(init_deter[tid]);
    d_s[tid] = dv;
    dinit[tid] = dv;
    __syncthreads();
    float acc = 0.f;
    for (int k = 0; k < 512; ++k) acc += d_s[k] * W_po[k * 512 + tid];
    float v[2] = {acc, acc * acc};
    breduce<2>(v, red, 8);
    float m = v[0] / 512.f, va = v[1] / 512.f - m * m, iv = rsqrtf(va + LNEPS);
    h_s[tid] = siluf_((acc - m) * iv * g_po[tid] + b_po[tid]);
    __syncthreads();
    if (tid < 32) {
        float s = b_ps[tid];
        for (int k = 0; k < 512; ++k) s += h_s[k] * W_ps[k * 64 + tid];
        sinit[tid] = s;
    }
}

__global__ __launch_bounds__(256) void k_transpose_bf(const float* __restrict__ src,
                                                      __hip_bfloat16* __restrict__ dst, int K, int N) {
    __shared__ float tle[32][33];
    int nTK = K >> 5;
    int k0 = (blockIdx.x % nTK) * 32;
    int n0 = (blockIdx.x / nTK) * 32;
    int tx = threadIdx.x & 31, ty = threadIdx.x >> 5;
#pragma unroll
    for (int i = 0; i < 4; ++i) tle[ty + i * 8][tx] = src[(size_t)(k0 + ty + i * 8) * N + n0 + tx];
    __syncthreads();
#pragma unroll
    for (int i = 0; i < 4; ++i)
        dst[(size_t)(n0 + ty + i * 8) * K + k0 + tx] = __float2bfloat16(tle[tx][ty + i * 8]);
}

__global__ __launch_bounds__(256) void k_cvt_bf(const float* __restrict__ src, __hip_bfloat16* __restrict__ dst,
                                                int n) {
    for (int i = blockIdx.x * 256 + threadIdx.x; i < n; i += gridDim.x * 256) dst[i] = __float2bfloat16(src[i]);
}

extern "C" void kernel_launch(void* const* d_in, const int* in_sizes, int n_in, void* d_out, int out_size, void* d_ws,
                              size_t ws_size, hipStream_t stream) {
    const float* obs = (const float*)d_in[0];
    const float* action = (const float*)d_in[1];
    const int* is_first = (const int*)d_in[2];
    const float* W_pi = (const float*)d_in[3];
    const float* g_pi = (const float*)d_in[4];
    const float* b_pi = (const float*)d_in[5];
    const float* W_gru = (const float*)d_in[6];
    const float* g_gru = (const float*)d_in[7];
    const float* b_gru = (const float*)d_in[8];
    const float* W_po = (const float*)d_in[9];
    const float* g_po = (const float*)d_in[10];
    const float* b_po = (const float*)d_in[11];
    const float* W_ps = (const float*)d_in[12];
    const float* b_ps = (const float*)d_in[13];
    const float* W_pn = (const float*)d_in[14];
    const float* g_pn = (const float*)d_in[15];
    const float* b_pn = (const float*)d_in[16];
    const float* W_pt = (const float*)d_in[17];
    const float* b_pt = (const float*)d_in[18];
    const float* init_deter = (const float*)d_in[19];
    float* out = (float*)d_out;

    char* p = (char*)d_ws;
    auto alloc = [&](size_t bytes) {
        char* r = p;
        p += (bytes + 255) & ~(size_t)255;
        return r;
    };
    float* gates = (float*)alloc((size_t)2 * BB * G3N * 4);   // 2 K-split partials
    float* deter = (float*)alloc((size_t)BB * 512 * 4);
    float* hq_raw = (float*)alloc((size_t)2 * BB * 512 * 4);  // 2 K-split partials
    float* dinit = (float*)alloc(512 * 4);
    float* sinit = (float*)alloc(64 * 4);
    __hip_bfloat16* xbf = (__hip_bfloat16*)alloc((size_t)BB * 512 * 2);
    __hip_bfloat16* dbf = (__hip_bfloat16*)alloc((size_t)BB * 512 * 2);
    __hip_bfloat16* obsbf = (__hip_bfloat16*)alloc((size_t)BB * TT * OBSN * 2);
    __hip_bfloat16* WgT = (__hip_bfloat16*)alloc((size_t)G3N * 1024 * 2);
    __hip_bfloat16* WpoT = (__hip_bfloat16*)alloc((size_t)512 * 512 * 2);
    __hip_bfloat16* WpnT = (__hip_bfloat16*)alloc((size_t)512 * 576 * 2);
    __hip_bfloat16* WpsT = (__hip_bfloat16*)alloc((size_t)64 * 512 * 2);
    __hip_bfloat16* WptT = (__hip_bfloat16*)alloc((size_t)64 * 512 * 2);
    __hip_bfloat16* Wpibf = (__hip_bfloat16*)alloc((size_t)CATPI * 512 * 2);

    k_transpose_bf<<<(1024 / 32) * (G3N / 32), 256, 0, stream>>>(W_gru, WgT, 1024, G3N);
    k_transpose_bf<<<(512 / 32) * (512 / 32), 256, 0, stream>>>(W_po, WpoT, 512, 512);
    k_transpose_bf<<<(576 / 32) * (512 / 32), 256, 0, stream>>>(W_pn, WpnT, 576, 512);
    k_transpose_bf<<<(512 / 32) * (64 / 32), 256, 0, stream>>>(W_ps, WpsT, 512, 64);
    k_transpose_bf<<<(512 / 32) * (64 / 32), 256, 0, stream>>>(W_pt, WptT, 512, 64);
    k_cvt_bf<<<80, 256, 0, stream>>>(W_pi, Wpibf, CATPI * 512);
    k_cvt_bf<<<2048, 256, 0, stream>>>(obs, obsbf, BB * TT * OBSN);
    k_init<<<1, 512, 0, stream>>>(init_deter, W_po, g_po, b_po, W_ps, b_ps, dinit, sinit);
    k_prior0<<<256, 256, 0, stream>>>(is_first, action, dinit, sinit, Wpibf, g_pi, b_pi, deter, dbf, xbf);

    for (int t = 0; t < TT; ++t) {
        k_gemm_gru<<<1024, 256, 0, stream>>>(xbf, dbf, WgT, gates);
        k_update<<<256, 256, 0, stream>>>(t, gates, g_gru, b_gru, deter, dbf, out);
        k_gemm_hq<<<512, 256, 0, stream>>>(t, dbf, obsbf, WpnT, hq_raw);
        k_finish<<<256, 256, 0, stream>>>(t, hq_raw, g_pn, b_pn, WptT, b_pt, is_first, action, dinit, sinit, deter,
                                          dbf, Wpibf, g_pi, b_pi, xbf, out);
    }
    k_post_p<<<BB * TT / 64, 512, 0, stream>>>(out, WpoT, g_po, b_po, WpsT, b_ps, out);
}

// Round 18
// 2271.137 us; speedup vs baseline: 1.0730x; 1.0730x over previous
//
#include <hip/hip_runtime.h>
#include <hip/hip_bf16.h>
#include <math.h>

#define BB 1024
#define TT 64
#define OBSN 64
#define ACTN 8
#define STOCHN 32
#define DETERN 512
#define HIDN 512
#define G3N 1536
#define CATPI 40
#define OUTC 672
#define LNEPS 1e-3f
#define MINSTD 0.1f
#define UPDBIAS -1.0f

typedef __attribute__((ext_vector_type(8))) short short8;
typedef __attribute__((ext_vector_type(4))) float f32x4;

__device__ __forceinline__ float sigmoidf_(float x) { return 1.f / (1.f + expf(-x)); }
__device__ __forceinline__ float siluf_(float x) { return x / (1.f + expf(-x)); }
__device__ __forceinline__ float softplusf_(float x) { return (x > 20.f) ? x : log1pf(expf(x)); }

__device__ __forceinline__ float b2f(short u) {
    unsigned x = ((unsigned)(unsigned short)u) << 16;
    return __builtin_bit_cast(float, x);
}
__device__ __forceinline__ short f2b(float f) {
    __hip_bfloat16 h = __float2bfloat16(f);
    return __builtin_bit_cast(short, h);
}

__device__ __forceinline__ f32x4 mfma16(short8 a, short8 b, f32x4 c) {
    return __builtin_amdgcn_mfma_f32_16x16x32_bf16(a, b, c, 0, 0, 0);
}

__device__ __forceinline__ void gload_lds16(const void* g, void* l) {
    __builtin_amdgcn_global_load_lds((const __attribute__((address_space(1))) void*)g,
                                     (__attribute__((address_space(3))) void*)l, 16, 0, 0);
}

__device__ __forceinline__ void wred2(float& a, float& b) {
#pragma unroll
    for (int off = 32; off; off >>= 1) {
        a += __shfl_xor(a, off);
        b += __shfl_xor(b, off);
    }
}

// ---- swizzled bf16 [R][512] LDS tile: row stride 1024 B, 16B slots XOR'd by row&7 ----
__device__ __forceinline__ short8 frag_ld(const short* base, int row, int ks, int lk) {
    int slot = (ks * 4 + lk) ^ (row & 7);
    return *(const short8*)((const char*)base + row * 1024 + (slot << 4));
}
// ---- swizzled bf16 rows of 64 K (128 B stride) ----
__device__ __forceinline__ short8 frag_ld64(const short* base, int row, int ks, int lk) {
    int slot = ((ks * 4 + lk) ^ (row & 7)) & 7;
    return *(const short8*)((const char*)base + row * 128 + (slot << 4));
}

// ==== GEMM tile machinery, parameterized: BM = AMT*32, BN = NFC*32, C type CT ====
template <int NFC, int AMT>
__device__ __forceinline__ void stage_tile(const __hip_bfloat16* A0, int ld0, int K0, const __hip_bfloat16* A1,
                                           int ld1, const __hip_bfloat16* Wt, int ldW, int wn0, int cm0, int k0,
                                           char* smA, char* smB) {
    int tid = threadIdx.x, wid = tid >> 6, lane = tid & 63;
    int rseg = lane >> 3, slot = lane & 7;
    const __hip_bfloat16* Ab;
    int ldA, kloc;
    if (k0 < K0) {
        Ab = A0; ldA = ld0; kloc = k0;
    } else {
        Ab = A1; ldA = ld1; kloc = k0 - K0;
    }
#pragma unroll
    for (int i = 0; i < AMT; ++i) {
        int seg = wid * AMT + i;
        int row = seg * 8 + rseg;
        int kk = kloc + ((slot ^ (row & 7)) << 3);
        gload_lds16(Ab + (size_t)(cm0 + row) * ldA + kk, smA + seg * 1024);
    }
#pragma unroll
    for (int i = 0; i < NFC; ++i) {
        int seg = wid * NFC + i;
        int row = seg * 8 + rseg;
        int kk = k0 + ((slot ^ (row & 7)) << 3);
        gload_lds16(Wt + (size_t)(wn0 + row) * ldW + kk, smB + seg * 1024);
    }
}

template <int NFC, int AMT>
__device__ __forceinline__ void compute_tile(const char* smA, const char* smB, f32x4 (&acc)[AMT][NFC]) {
    int lane = threadIdx.x & 63, wid = threadIdx.x >> 6;
    int wr = wid >> 1, wc = wid & 1;
#pragma unroll
    for (int ks = 0; ks < 2; ++ks) {
        short8 af[AMT], bfr[NFC];
        int kslot = ks * 4 + (lane >> 4);
#pragma unroll
        for (int m = 0; m < AMT; ++m) {
            int row = wr * (16 * AMT) + m * 16 + (lane & 15);
            af[m] = *(const short8*)(smA + row * 128 + ((kslot ^ (row & 7)) << 4));
        }
#pragma unroll
        for (int n = 0; n < NFC; ++n) {
            int row = wc * (16 * NFC) + n * 16 + (lane & 15);
            bfr[n] = *(const short8*)(smB + row * 128 + ((kslot ^ (row & 7)) << 4));
        }
#pragma unroll
        for (int m = 0; m < AMT; ++m)
#pragma unroll
            for (int n = 0; n < NFC; ++n) acc[m][n] = mfma16(af[m], bfr[n], acc[m][n]);
    }
}

template <int NFC, int AMT, typename CT>
__device__ __forceinline__ void gemm_tile_db(const __hip_bfloat16* A0, int ld0, int K0, const __hip_bfloat16* A1,
                                             int ld1, const __hip_bfloat16* Wt, int ldW, int wn0, CT* C, int ldc,
                                             int cm0, int cn0, int nK, char* smem) {
    char* smA[2] = {smem, smem + AMT * 4096};
    char* smB[2] = {smem + 2 * AMT * 4096, smem + 2 * AMT * 4096 + NFC * 4096};
    f32x4 acc[AMT][NFC] = {};
    stage_tile<NFC, AMT>(A0, ld0, K0, A1, ld1, Wt, ldW, wn0, cm0, 0, smA[0], smB[0]);
    for (int kt = 0; kt < nK; ++kt) {
        if (kt + 1 < nK) {
            stage_tile<NFC, AMT>(A0, ld0, K0, A1, ld1, Wt, ldW, wn0, cm0, (kt + 1) * 64, smA[(kt + 1) & 1],
                                 smB[(kt + 1) & 1]);
            constexpr int NL = NFC + AMT;
            if constexpr (NL == 5) asm volatile("s_waitcnt vmcnt(5)" ::: "memory");
            else if constexpr (NL == 4) asm volatile("s_waitcnt vmcnt(4)" ::: "memory");
            else asm volatile("s_waitcnt vmcnt(3)" ::: "memory");
        } else {
            asm volatile("s_waitcnt vmcnt(0)" ::: "memory");
        }
        __builtin_amdgcn_s_barrier();
        compute_tile<NFC, AMT>(smA[kt & 1], smB[kt & 1], acc);
        __builtin_amdgcn_s_barrier();
    }
    int lane = threadIdx.x & 63, wid = threadIdx.x >> 6;
    int wr = wid >> 1, wc = wid & 1;
    int r0 = cm0 + wr * (16 * AMT) + ((lane >> 4) << 2);
    int c0 = cn0 + wc * 16 * NFC + (lane & 15);
#pragma unroll
    for (int m = 0; m < AMT; ++m)
#pragma unroll
        for (int n = 0; n < NFC; ++n)
#pragma unroll
            for (int i = 0; i < 4; ++i) {
                if constexpr (__is_same(CT, float))
                    C[(size_t)(r0 + m * 16 + i) * ldc + c0 + n * 16] = acc[m][n][i];
                else
                    C[(size_t)(r0 + m * 16 + i) * ldc + c0 + n * 16] =
                        __builtin_bit_cast(__hip_bfloat16, f2b(acc[m][n][i]));
            }
}

// ==== K1: GRU GEMM, 512 blocks of 32x96 (2 blocks/CU), bf16 C ====
__global__ __launch_bounds__(256) void k_gemm_gru(const __hip_bfloat16* __restrict__ xbf,
                                                  const __hip_bfloat16* __restrict__ dbf,
                                                  const __hip_bfloat16* __restrict__ WgT,
                                                  __hip_bfloat16* __restrict__ gates) {
    __shared__ __align__(16) char smem[32768];
    int bm = blockIdx.x & 31, bn = blockIdx.x >> 5;  // 32 x 16
    gemm_tile_db<3, 1>(xbf, 512, 512, dbf, 512, WgT, 1024, bn * 96, gates, G3N, bm * 32, bn * 96, 16, smem);
}

// ==== K2: LN(gates bf16) + GRU update. 256 blocks x 256 thr (4 rows/block) ====
__global__ __launch_bounds__(256) void k_update(int t, const __hip_bfloat16* __restrict__ gates,
                                                const float* __restrict__ g_gru, const float* __restrict__ b_gru,
                                                float* __restrict__ deter, __hip_bfloat16* __restrict__ dbf,
                                                float* __restrict__ out) {
    const int tid = threadIdx.x;
    const int prow = tid >> 6, l = tid & 63;
    const int gr = blockIdx.x * 4 + prow;
    const int j0 = l * 8;
    const __hip_bfloat16* gp = gates + (size_t)gr * G3N;
    float g0[8], g1[8], g2[8];
    float s = 0.f, q = 0.f;
    {
        short8 a = *(const short8*)(gp + j0);
        short8 b = *(const short8*)(gp + 512 + j0);
        short8 c = *(const short8*)(gp + 1024 + j0);
#pragma unroll
        for (int u = 0; u < 8; ++u) {
            float av = b2f(a[u]), bv = b2f(b[u]), cv = b2f(c[u]);
            g0[u] = av;
            g1[u] = bv;
            g2[u] = cv;
            s += av + bv + cv;
            q += av * av + bv * bv + cv * cv;
        }
    }
    wred2(s, q);
    float m = s * (1.f / 1536.f), iv = rsqrtf(q * (1.f / 1536.f) - m * m + LNEPS);
    float dn[8];
    float* dp = deter + (size_t)gr * 512 + j0;
#pragma unroll
    for (int e = 0; e < 8; e += 4) {
        f32x4 dv = *(const f32x4*)(dp + e);
#pragma unroll
        for (int u = 0; u < 4; ++u) {
            int col = j0 + e + u;
            float rv = sigmoidf_((g0[e + u] - m) * iv * g_gru[col] + b_gru[col]);
            float cv = (g1[e + u] - m) * iv * g_gru[512 + col] + b_gru[512 + col];
            float uv = sigmoidf_((g2[e + u] - m) * iv * g_gru[1024 + col] + b_gru[1024 + col] + UPDBIAS);
            dn[e + u] = uv * siluf_(rv * cv) + (1.f - uv) * dv[u];
        }
    }
    size_t ob = ((size_t)gr * TT + t) * OUTC + 160 + j0;
    short8 h;
#pragma unroll
    for (int e = 0; e < 8; e += 4) {
        *(f32x4*)(dp + e) = *(const f32x4*)&dn[e];
        *(f32x4*)(out + ob + e) = *(const f32x4*)&dn[e];
    }
#pragma unroll
    for (int u = 0; u < 8; ++u) h[u] = f2b(dn[u]);
    *(short8*)(dbf + (size_t)gr * 512 + j0) = h;
}

// ==== K3: hq_raw = cat(deter_n, obs_t) @ W_pn. 256 blocks of 32x64, K=576 ====
__global__ __launch_bounds__(256) void k_gemm_hq(int t, const __hip_bfloat16* __restrict__ dbf,
                                                 const __hip_bfloat16* __restrict__ obsbf,
                                                 const __hip_bfloat16* __restrict__ WpnT,
                                                 float* __restrict__ hq_raw) {
    __shared__ __align__(16) char smem[24576];
    int bm = blockIdx.x & 31, bn = blockIdx.x >> 5;  // 32 x 8
    gemm_tile_db<2, 1>(dbf, 512, 512, obsbf + (size_t)t * OBSN, TT * OBSN, WpnT, 576, bn * 64, hq_raw, 512,
                       bm * 32, bn * 64, 9, smem);
}

// ==== K4: LN(hq)+silu, qs stats, outputs, reset, next prior_in. 256 blocks x 256 thr (4 rows) ====
__global__ __launch_bounds__(256) void k_finish(int t, const float* __restrict__ hq_raw,
                                                const float* __restrict__ g_pn, const float* __restrict__ b_pn,
                                                const __hip_bfloat16* __restrict__ WptT,
                                                const float* __restrict__ b_pt, const int* __restrict__ isf,
                                                const float* __restrict__ action, const float* __restrict__ dinit,
                                                const float* __restrict__ sinit, float* __restrict__ deter,
                                                __hip_bfloat16* __restrict__ dbf,
                                                const __hip_bfloat16* __restrict__ Wpibf,
                                                const float* __restrict__ g_pi, const float* __restrict__ b_pi,
                                                __hip_bfloat16* __restrict__ xbf, float* __restrict__ out) {
    __shared__ float hql[4][512];
    __shared__ float a_ls[4][40];
    const int wid = threadIdx.x >> 6, l = threadIdx.x & 63;
    const int gr = blockIdx.x * 4 + wid;
    const int j0 = l * 8;
    const float* hr = hq_raw + (size_t)gr * 512;
    float h[8];
    *(f32x4*)&h[0] = *(const f32x4*)(hr + j0);
    *(f32x4*)&h[4] = *(const f32x4*)(hr + j0 + 4);
    float s = 0.f, q = 0.f;
#pragma unroll
    for (int e = 0; e < 8; ++e) {
        s += h[e];
        q += h[e] * h[e];
    }
    wred2(s, q);
    float m = s * (1.f / 512.f), iv = rsqrtf(q * (1.f / 512.f) - m * m + LNEPS);
#pragma unroll
    for (int e = 0; e < 8; ++e) h[e] = siluf_((h[e] - m) * iv * g_pn[j0 + e] + b_pn[j0 + e]);
    *(f32x4*)&hql[wid][j0] = *(const f32x4*)&h[0];
    *(f32x4*)&hql[wid][j0 + 4] = *(const f32x4*)&h[4];
    __syncthreads();
    float acc = b_pt[l];
    const __hip_bfloat16* wr = WptT + (size_t)l * 512;
    const float* hq = hql[wid];
#pragma unroll 4
    for (int k0 = 0; k0 < 512; k0 += 8) {
        short8 w = *(const short8*)(wr + k0);
        f32x4 a0 = *(const f32x4*)(hq + k0);
        f32x4 a1 = *(const f32x4*)(hq + k0 + 4);
#pragma unroll
        for (int e = 0; e < 4; ++e) {
            acc += b2f(w[e]) * a0[e];
            acc += b2f(w[4 + e]) * a1[e];
        }
    }
    size_t ob = ((size_t)gr * TT + t) * OUTC;
    if (l < 32) {
        out[ob + l] = acc;
        out[ob + 64 + l] = acc;
    } else {
        out[ob + 32 + (l - 32)] = softplusf_(acc) + MINSTD;
    }
    if (t + 1 >= TT) return;
    int f1 = isf[(size_t)gr * TT + t + 1] > 0;
    if (l < 32)
        a_ls[wid][l] = f1 ? sinit[l] : acc;
    else if (l < 40)
        a_ls[wid][l] = f1 ? 0.f : action[((size_t)gr * TT + t + 1) * ACTN + (l - 32)];
    if (f1) {
        f32x4 d0 = *(const f32x4*)(dinit + j0);
        f32x4 d1 = *(const f32x4*)(dinit + j0 + 4);
        *(f32x4*)(deter + (size_t)gr * 512 + j0) = d0;
        *(f32x4*)(deter + (size_t)gr * 512 + j0 + 4) = d1;
        short8 db;
#pragma unroll
        for (int e = 0; e < 4; ++e) {
            db[e] = f2b(d0[e]);
            db[4 + e] = f2b(d1[e]);
        }
        *(short8*)(dbf + (size_t)gr * 512 + j0) = db;
    }
    __syncthreads();
    float o[8] = {};
    const float* a_s = a_ls[wid];
    for (int k = 0; k < CATPI; ++k) {
        float a = a_s[k];
        short8 w = *(const short8*)(Wpibf + k * 512 + j0);
#pragma unroll
        for (int e = 0; e < 8; ++e) o[e] += a * b2f(w[e]);
    }
    float s2 = 0.f, q2 = 0.f;
#pragma unroll
    for (int e = 0; e < 8; ++e) {
        s2 += o[e];
        q2 += o[e] * o[e];
    }
    wred2(s2, q2);
    float m2 = s2 * (1.f / 512.f), iv2 = rsqrtf(q2 * (1.f / 512.f) - m2 * m2 + LNEPS);
    short8 xo;
#pragma unroll
    for (int e = 0; e < 8; ++e) xo[e] = f2b(siluf_((o[e] - m2) * iv2 * g_pi[j0 + e] + b_pi[j0 + e]));
    *(short8*)(xbf + (size_t)gr * 512 + j0) = xo;
}

// ==== deferred p_mean/p_std: 1024 blocks x 512 thr, M=64/block (round-14 validated: 148 us) ====
__global__ __launch_bounds__(512) void k_post_p(const float* __restrict__ outr,
                                                const __hip_bfloat16* __restrict__ WpoT,
                                                const float* __restrict__ g_po, const float* __restrict__ b_po,
                                                const __hip_bfloat16* __restrict__ WpsT,
                                                const float* __restrict__ b_ps, float* __restrict__ out) {
    __shared__ short Abuf[64 * 512];
    __shared__ __align__(16) short Wbuf[512 * 64];
    __shared__ float red[8 * 64 * 2];
    __shared__ float redc[64 * 2];
    const int tid = threadIdx.x, wid = tid >> 6, lane = tid & 63, lr = lane & 15, lk = lane >> 4;
    const int base = blockIdx.x * 64;
    const int c0 = wid * 64 + lr;

#pragma unroll
    for (int it = 0; it < 8; ++it) {
        int idx = it * 512 + tid;
        int row = idx >> 6, slot = idx & 63;
        int k = (slot ^ (row & 7)) << 3;
        const float* src = outr + ((size_t)(base + row) * OUTC + 160 + k);
        f32x4 a = *(const f32x4*)src;
        f32x4 bb = *(const f32x4*)(src + 4);
        short8 v;
#pragma unroll
        for (int e = 0; e < 4; ++e) {
            v[e] = f2b(a[e]);
            v[4 + e] = f2b(bb[e]);
        }
        *(short8*)((char*)Abuf + idx * 16) = v;
    }
    auto stageW = [&](int ck) {
#pragma unroll
        for (int i = 0; i < 8; ++i) {
            int seg = wid * 8 + i;
            int row = seg * 8 + (lane >> 3);
            int kk = ck * 64 + (((lane & 7) ^ (row & 7)) << 3);
            gload_lds16(WpoT + (size_t)row * 512 + kk, (char*)Wbuf + seg * 1024);
        }
    };
    __syncthreads();
    f32x4 acc[4][4] = {};
    for (int ck = 0; ck < 8; ++ck) {
        stageW(ck);
        asm volatile("s_waitcnt vmcnt(0)" ::: "memory");
        __builtin_amdgcn_s_barrier();
#pragma unroll
        for (int ks = 0; ks < 2; ++ks) {
            short8 af[4];
#pragma unroll
            for (int rt = 0; rt < 4; ++rt) af[rt] = frag_ld(Abuf, rt * 16 + lr, ck * 2 + ks, lk);
#pragma unroll
            for (int f = 0; f < 4; ++f) {
                short8 bf = frag_ld64(Wbuf, c0 + f * 16, ks, lk);
#pragma unroll
                for (int rt = 0; rt < 4; ++rt) acc[rt][f] = mfma16(af[rt], bf, acc[rt][f]);
            }
        }
        __builtin_amdgcn_s_barrier();
    }
#pragma unroll
    for (int qq = 0; qq < 8; ++qq) {
        int sI = qq * 512 + tid;
        int row = sI >> 6, slot = sI & 63;
        int k = (slot ^ (row & 7)) << 3;
        gload_lds16(WpsT + (size_t)row * 512 + k, (char*)Abuf + (qq * 512 + wid * 64) * 16);
    }
    {
        float s[4][4], q[4][4];
#pragma unroll
        for (int rt = 0; rt < 4; ++rt)
#pragma unroll
            for (int i = 0; i < 4; ++i) {
                float ss = 0.f, qq2 = 0.f;
#pragma unroll
                for (int f = 0; f < 4; ++f) {
                    float v = acc[rt][f][i];
                    ss += v;
                    qq2 += v * v;
                }
                s[rt][i] = ss;
                q[rt][i] = qq2;
            }
#pragma unroll
        for (int msk = 1; msk <= 8; msk <<= 1)
#pragma unroll
            for (int rt = 0; rt < 4; ++rt)
#pragma unroll
                for (int i = 0; i < 4; ++i) {
                    s[rt][i] += __shfl_xor(s[rt][i], msk);
                    q[rt][i] += __shfl_xor(q[rt][i], msk);
                }
        if (lr == 0)
#pragma unroll
            for (int rt = 0; rt < 4; ++rt)
#pragma unroll
                for (int i = 0; i < 4; ++i) {
                    int row = rt * 16 + lk * 4 + i;
                    red[(wid * 64 + row) * 2 + 0] = s[rt][i];
                    red[(wid * 64 + row) * 2 + 1] = q[rt][i];
                }
        __syncthreads();
        if (tid < 128) {
            int row = tid >> 1, v = tid & 1;
            float a = 0.f;
#pragma unroll
            for (int w = 0; w < 8; ++w) a += red[(w * 64 + row) * 2 + v];
            redc[row * 2 + v] = a;
        }
        __syncthreads();
#pragma unroll
        for (int rt = 0; rt < 4; ++rt)
#pragma unroll
            for (int i = 0; i < 4; ++i) {
                int row = rt * 16 + lk * 4 + i;
                float mm = redc[row * 2] * (1.f / 512.f);
                float vv = redc[row * 2 + 1] * (1.f / 512.f) - mm * mm;
                float ivv = rsqrtf(vv + LNEPS);
#pragma unroll
                for (int f = 0; f < 4; ++f) {
                    int col = c0 + f * 16;
                    float v = siluf_((acc[rt][f][i] - mm) * ivv * g_po[col] + b_po[col]);
                    *(short*)((char*)Wbuf + row * 1024 +
                              ((((col >> 3) ^ (row & 7)) << 4) | ((col & 7) << 1))) = f2b(v);
                }
            }
    }
    asm volatile("s_waitcnt vmcnt(0)" ::: "memory");
    __syncthreads();
    if (wid < 4) {
        int col = wid * 16 + lr;
        f32x4 ap[4] = {};
#pragma unroll 2
        for (int ks = 0; ks < 16; ++ks) {
            short8 bfr = frag_ld(Abuf, col, ks, lk);
#pragma unroll
            for (int rt = 0; rt < 4; ++rt) {
                short8 a = frag_ld(Wbuf, rt * 16 + lr, ks, lk);
                ap[rt] = mfma16(a, bfr, ap[rt]);
            }
        }
        float bias = b_ps[col];
#pragma unroll
        for (int rt = 0; rt < 4; ++rt)
#pragma unroll
            for (int i = 0; i < 4; ++i) {
                int gidx = base + rt * 16 + lk * 4 + i;
                float v = ap[rt][i] + bias;
                if (col < 32)
                    out[(size_t)gidx * OUTC + 96 + col] = v;
                else
                    out[(size_t)gidx * OUTC + 128 + (col - 32)] = softplusf_(v) + MINSTD;
            }
    }
}

// ==== t=0 state + first prior_in (256 blocks x 256 thr, 4 rows) ====
__global__ __launch_bounds__(256) void k_prior0(const int* __restrict__ isf, const float* __restrict__ action,
                                                const float* __restrict__ dinit, const float* __restrict__ sinit,
                                                const __hip_bfloat16* __restrict__ Wpibf,
                                                const float* __restrict__ g_pi, const float* __restrict__ b_pi,
                                                float* __restrict__ deter0, __hip_bfloat16* __restrict__ dbf,
                                                __hip_bfloat16* __restrict__ xbf) {
    __shared__ float a_ls[4][40];
    const int wid = threadIdx.x >> 6, l = threadIdx.x & 63;
    const int gr = blockIdx.x * 4 + wid;
    const int j0 = l * 8;
    int f0 = isf[(size_t)gr * TT] > 0;
    if (l < 32)
        a_ls[wid][l] = sinit[l];
    else if (l < 40)
        a_ls[wid][l] = f0 ? 0.f : action[(size_t)gr * TT * ACTN + (l - 32)];
    f32x4 d0 = *(const f32x4*)(dinit + j0);
    f32x4 d1 = *(const f32x4*)(dinit + j0 + 4);
    *(f32x4*)(deter0 + (size_t)gr * 512 + j0) = d0;
    *(f32x4*)(deter0 + (size_t)gr * 512 + j0 + 4) = d1;
    short8 db;
#pragma unroll
    for (int e = 0; e < 4; ++e) {
        db[e] = f2b(d0[e]);
        db[4 + e] = f2b(d1[e]);
    }
    *(short8*)(dbf + (size_t)gr * 512 + j0) = db;
    __syncthreads();
    float o[8] = {};
    const float* a_s = a_ls[wid];
    for (int k = 0; k < CATPI; ++k) {
        float a = a_s[k];
        short8 w = *(const short8*)(Wpibf + k * 512 + j0);
#pragma unroll
        for (int e = 0; e < 8; ++e) o[e] += a * b2f(w[e]);
    }
    float s2 = 0.f, q2 = 0.f;
#pragma unroll
    for (int e = 0; e < 8; ++e) {
        s2 += o[e];
        q2 += o[e] * o[e];
    }
    wred2(s2, q2);
    float m2 = s2 * (1.f / 512.f), iv2 = rsqrtf(q2 * (1.f / 512.f) - m2 * m2 + LNEPS);
    short8 xo;
#pragma unroll
    for (int e = 0; e < 8; ++e) xo[e] = f2b(siluf_((o[e] - m2) * iv2 * g_pi[j0 + e] + b_pi[j0 + e]));
    *(short8*)(xbf + (size_t)gr * 512 + j0) = xo;
}

// ---- block-wide reduction (k_init only) ----
template <int NV>
__device__ __forceinline__ void breduce(float* v, float* red, int nwaves) {
    __syncthreads();
#pragma unroll
    for (int off = 32; off > 0; off >>= 1)
#pragma unroll
        for (int q = 0; q < NV; ++q) v[q] += __shfl_down(v[q], off);
    int lane = threadIdx.x & 63, w = threadIdx.x >> 6;
    if (lane == 0)
        for (int q = 0; q < NV; ++q) red[w * NV + q] = v[q];
    __syncthreads();
    if ((int)threadIdx.x < NV) {
        float s = 0.f;
        for (int ww = 0; ww < nwaves; ++ww) s += red[ww * NV + threadIdx.x];
        red[nwaves * NV + threadIdx.x] = s;
    }
    __syncthreads();
#pragma unroll
    for (int q = 0; q < NV; ++q) v[q] = red[nwaves * NV + q];
}

__global__ __launch_bounds__(512) void k_init(const float* __restrict__ init_deter, const float* __restrict__ W_po,
                                              const float* __restrict__ g_po, const float* __restrict__ b_po,
                                              const float* __restrict__ W_ps, const float* __restrict__ b_ps,
                                              float* __restrict__ dinit, float* __restrict__ sinit) {
    __shared__ float d_s[512], h_s[512], red[40];
    int tid = threadIdx.x;
    float dv = tanhf(init_deter[tid]);
    d_s[tid] = dv;
    dinit[tid] = dv;
    __syncthreads();
    float acc = 0.f;
    for (int k = 0; k < 512; ++k) acc += d_s[k] * W_po[k * 512 + tid];
    float v[2] = {acc, acc * acc};
    breduce<2>(v, red, 8);
    float m = v[0] / 512.f, va = v[1] / 512.f - m * m, iv = rsqrtf(va + LNEPS);
    h_s[tid] = siluf_((acc - m) * iv * g_po[tid] + b_po[tid]);
    __syncthreads();
    if (tid < 32) {
        float s = b_ps[tid];
        for (int k = 0; k < 512; ++k) s += h_s[k] * W_ps[k * 64 + tid];
        sinit[tid] = s;
    }
}

__global__ __launch_bounds__(256) void k_transpose_bf(const float* __restrict__ src,
                                                      __hip_bfloat16* __restrict__ dst, int K, int N) {
    __shared__ float tle[32][33];
    int nTK = K >> 5;
    int k0 = (blockIdx.x % nTK) * 32;
    int n0 = (blockIdx.x / nTK) * 32;
    int tx = threadIdx.x & 31, ty = threadIdx.x >> 5;
#pragma unroll
    for (int i = 0; i < 4; ++i) tle[ty + i * 8][tx] = src[(size_t)(k0 + ty + i * 8) * N + n0 + tx];
    __syncthreads();
#pragma unroll
    for (int i = 0; i < 4; ++i)
        dst[(size_t)(n0 + ty + i * 8) * K + k0 + tx] = __float2bfloat16(tle[tx][ty + i * 8]);
}

__global__ __launch_bounds__(256) void k_cvt_bf(const float* __restrict__ src, __hip_bfloat16* __restrict__ dst,
                                                int n) {
    for (int i = blockIdx.x * 256 + threadIdx.x; i < n; i += gridDim.x * 256) dst[i] = __float2bfloat16(src[i]);
}

extern "C" void kernel_launch(void* const* d_in, const int* in_sizes, int n_in, void* d_out, int out_size, void* d_ws,
                              size_t ws_size, hipStream_t stream) {
    const float* obs = (const float*)d_in[0];
    const float* action = (const float*)d_in[1];
    const int* is_first = (const int*)d_in[2];
    const float* W_pi = (const float*)d_in[3];
    const float* g_pi = (const float*)d_in[4];
    const float* b_pi = (const float*)d_in[5];
    const float* W_gru = (const float*)d_in[6];
    const float* g_gru = (const float*)d_in[7];
    const float* b_gru = (const float*)d_in[8];
    const float* W_po = (const float*)d_in[9];
    const float* g_po = (const float*)d_in[10];
    const float* b_po = (const float*)d_in[11];
    const float* W_ps = (const float*)d_in[12];
    const float* b_ps = (const float*)d_in[13];
    const float* W_pn = (const float*)d_in[14];
    const float* g_pn = (const float*)d_in[15];
    const float* b_pn = (const float*)d_in[16];
    const float* W_pt = (const float*)d_in[17];
    const float* b_pt = (const float*)d_in[18];
    const float* init_deter = (const float*)d_in[19];
    float* out = (float*)d_out;

    char* p = (char*)d_ws;
    auto alloc = [&](size_t bytes) {
        char* r = p;
        p += (bytes + 255) & ~(size_t)255;
        return r;
    };
    __hip_bfloat16* gates = (__hip_bfloat16*)alloc((size_t)BB * G3N * 2);
    float* deter = (float*)alloc((size_t)BB * 512 * 4);
    float* hq_raw = (float*)alloc((size_t)BB * 512 * 4);
    float* dinit = (float*)alloc(512 * 4);
    float* sinit = (float*)alloc(64 * 4);
    __hip_bfloat16* xbf = (__hip_bfloat16*)alloc((size_t)BB * 512 * 2);
    __hip_bfloat16* dbf = (__hip_bfloat16*)alloc((size_t)BB * 512 * 2);
    __hip_bfloat16* obsbf = (__hip_bfloat16*)alloc((size_t)BB * TT * OBSN * 2);
    __hip_bfloat16* WgT = (__hip_bfloat16*)alloc((size_t)G3N * 1024 * 2);
    __hip_bfloat16* WpoT = (__hip_bfloat16*)alloc((size_t)512 * 512 * 2);
    __hip_bfloat16* WpnT = (__hip_bfloat16*)alloc((size_t)512 * 576 * 2);
    __hip_bfloat16* WpsT = (__hip_bfloat16*)alloc((size_t)64 * 512 * 2);
    __hip_bfloat16* WptT = (__hip_bfloat16*)alloc((size_t)64 * 512 * 2);
    __hip_bfloat16* Wpibf = (__hip_bfloat16*)alloc((size_t)CATPI * 512 * 2);

    k_transpose_bf<<<(1024 / 32) * (G3N / 32), 256, 0, stream>>>(W_gru, WgT, 1024, G3N);
    k_transpose_bf<<<(512 / 32) * (512 / 32), 256, 0, stream>>>(W_po, WpoT, 512, 512);
    k_transpose_bf<<<(576 / 32) * (512 / 32), 256, 0, stream>>>(W_pn, WpnT, 576, 512);
    k_transpose_bf<<<(512 / 32) * (64 / 32), 256, 0, stream>>>(W_ps, WpsT, 512, 64);
    k_transpose_bf<<<(512 / 32) * (64 / 32), 256, 0, stream>>>(W_pt, WptT, 512, 64);
    k_cvt_bf<<<80, 256, 0, stream>>>(W_pi, Wpibf, CATPI * 512);
    k_cvt_bf<<<2048, 256, 0, stream>>>(obs, obsbf, BB * TT * OBSN);
    k_init<<<1, 512, 0, stream>>>(init_deter, W_po, g_po, b_po, W_ps, b_ps, dinit, sinit);
    k_prior0<<<256, 256, 0, stream>>>(is_first, action, dinit, sinit, Wpibf, g_pi, b_pi, deter, dbf, xbf);

    for (int t = 0; t < TT; ++t) {
        k_gemm_gru<<<512, 256, 0, stream>>>(xbf, dbf, WgT, gates);
        k_update<<<256, 256, 0, stream>>>(t, gates, g_gru, b_gru, deter, dbf, out);
        k_gemm_hq<<<256, 256, 0, stream>>>(t, dbf, obsbf, WpnT, hq_raw);
        k_finish<<<256, 256, 0, stream>>>(t, hq_raw, g_pn, b_pn, WptT, b_pt, is_first, action, dinit, sinit, deter,
                                          dbf, Wpibf, g_pi, b_pi, xbf, out);
    }
    k_post_p<<<BB * TT / 64, 512, 0, stream>>>(out, WpoT, g_po, b_po, WpsT, b_ps, out);
}